// Round 1
// baseline (4844.950 us; speedup 1.0000x reference)
//
#include <hip/hip_runtime.h>
#include <math.h>

#define BB   64
#define NIN  512
#define NH   512
#define TT   512

// K1: u[t][b][h] = sum_i X[b][i][t] * Wax[i][h] + bx[h] + ba[h]
// Written directly into d_out at [t][b][h]; K2 overwrites in place with a_{t+1}.
// 64x64 (t x h) tile per block, fixed b. 256 threads, 4x4 outputs/thread, fp32.
__global__ __launch_bounds__(256) void inp_proj_kernel(
    const float* __restrict__ X, const float* __restrict__ Wax,
    const float* __restrict__ bx, const float* __restrict__ ba,
    float* __restrict__ out)
{
    __shared__ float Xs[16][64];   // [i_local][t_local]
    __shared__ float Ws[16][64];   // [i_local][h_local]

    const int b   = blockIdx.z;
    const int t0  = blockIdx.y * 64;
    const int h0  = blockIdx.x * 64;
    const int tid = threadIdx.x;
    const int r   = tid >> 4;         // 0..15 (row for loads, t-subtile for compute)
    const int tx  = tid & 15;         // 0..15 (h-subtile)
    const int c4  = tx * 4;           // 0..60

    const float* Xb = X + (size_t)b * NIN * TT;

    float c[4][4] = {};

    for (int i0 = 0; i0 < NIN; i0 += 16) {
        // Cooperative loads: each thread one float4 per tile.
        *(float4*)&Xs[r][c4] = *(const float4*)&Xb[(size_t)(i0 + r) * TT + t0 + c4];
        *(float4*)&Ws[r][c4] = *(const float4*)&Wax[(size_t)(i0 + r) * NH + h0 + c4];
        __syncthreads();
#pragma unroll
        for (int i = 0; i < 16; ++i) {
            float4 av = *(float4*)&Xs[i][r * 4];   // 4 t-values
            float4 bv = *(float4*)&Ws[i][tx * 4];  // 4 h-values
            c[0][0] += av.x * bv.x; c[0][1] += av.x * bv.y; c[0][2] += av.x * bv.z; c[0][3] += av.x * bv.w;
            c[1][0] += av.y * bv.x; c[1][1] += av.y * bv.y; c[1][2] += av.y * bv.z; c[1][3] += av.y * bv.w;
            c[2][0] += av.z * bv.x; c[2][1] += av.z * bv.y; c[2][2] += av.z * bv.z; c[2][3] += av.z * bv.w;
            c[3][0] += av.w * bv.x; c[3][1] += av.w * bv.y; c[3][2] += av.w * bv.z; c[3][3] += av.w * bv.w;
        }
        __syncthreads();
    }

    float bias[4];
#pragma unroll
    for (int j = 0; j < 4; ++j)
        bias[j] = bx[h0 + tx * 4 + j] + ba[h0 + tx * 4 + j];

#pragma unroll
    for (int ttl = 0; ttl < 4; ++ttl) {
        const int t = t0 + r * 4 + ttl;
        float4 v;
        v.x = c[ttl][0] + bias[0];
        v.y = c[ttl][1] + bias[1];
        v.z = c[ttl][2] + bias[2];
        v.w = c[ttl][3] + bias[3];
        *(float4*)&out[(size_t)t * (BB * NH) + (size_t)b * NH + h0 + tx * 4] = v;
    }
}

// K2: sequential scan. One block per batch element (64 blocks, 512 threads).
// a_{t+1}[h] = tanh(u[t][h] + sum_k a_t[k] * Waa[k][h]); overwrites u in d_out.
__global__ __launch_bounds__(512) void rnn_scan_kernel(
    const float* __restrict__ Waa, float* __restrict__ out)
{
    __shared__ float a_s[NH];
    const int tid = threadIdx.x;
    const int b   = blockIdx.x;

    a_s[tid] = 0.0f;

    float* ob = out + (size_t)b * NH;
    const float* Wcol = Waa + tid;   // column h = tid, stride NH over k

    for (int t = 0; t < TT; ++t) {
        float u = ob[(size_t)t * (BB * NH) + tid];
        __syncthreads();  // a_s ready (init or previous step's write)

        float acc0 = 0.f, acc1 = 0.f, acc2 = 0.f, acc3 = 0.f;
#pragma unroll 8
        for (int k = 0; k < NH; k += 4) {
            float4 av = *(const float4*)&a_s[k];   // broadcast read
            acc0 += av.x * Wcol[(size_t)(k + 0) * NH];
            acc1 += av.y * Wcol[(size_t)(k + 1) * NH];
            acc2 += av.z * Wcol[(size_t)(k + 2) * NH];
            acc3 += av.w * Wcol[(size_t)(k + 3) * NH];
        }
        float an = tanhf(u + ((acc0 + acc1) + (acc2 + acc3)));
        ob[(size_t)t * (BB * NH) + tid] = an;

        __syncthreads();  // everyone done reading a_s before overwrite
        a_s[tid] = an;
    }
}

extern "C" void kernel_launch(void* const* d_in, const int* in_sizes, int n_in,
                              void* d_out, int out_size, void* d_ws, size_t ws_size,
                              hipStream_t stream) {
    const float* X   = (const float*)d_in[0];
    const float* Wax = (const float*)d_in[1];
    const float* Waa = (const float*)d_in[2];
    const float* bx  = (const float*)d_in[3];
    const float* ba  = (const float*)d_in[4];
    float* out = (float*)d_out;

    dim3 g1(NH / 64, TT / 64, BB);
    inp_proj_kernel<<<g1, 256, 0, stream>>>(X, Wax, bx, ba, out);
    rnn_scan_kernel<<<BB, NH, 0, stream>>>(Waa, out);
}

// Round 2
// 4395.102 us; speedup vs baseline: 1.1024x; 1.1024x over previous
//
#include <hip/hip_runtime.h>
#include <math.h>

#define BB   64
#define NIN  512
#define NH   512
#define TT   512

// ---------------------------------------------------------------------------
// K1: u[t][b][h] = sum_i X[b][i][t] * Wax[i][h] + bx[h] + ba[h]
// Written directly into d_out at [t][b][h]; K2 overwrites in place with a_{t+1}.
// ---------------------------------------------------------------------------
__global__ __launch_bounds__(256) void inp_proj_kernel(
    const float* __restrict__ X, const float* __restrict__ Wax,
    const float* __restrict__ bx, const float* __restrict__ ba,
    float* __restrict__ out)
{
    __shared__ float Xs[16][64];   // [i_local][t_local]
    __shared__ float Ws[16][64];   // [i_local][h_local]

    const int b   = blockIdx.z;
    const int t0  = blockIdx.y * 64;
    const int h0  = blockIdx.x * 64;
    const int tid = threadIdx.x;
    const int r   = tid >> 4;
    const int tx  = tid & 15;
    const int c4  = tx * 4;

    const float* Xb = X + (size_t)b * NIN * TT;

    float c[4][4] = {};

    for (int i0 = 0; i0 < NIN; i0 += 16) {
        *(float4*)&Xs[r][c4] = *(const float4*)&Xb[(size_t)(i0 + r) * TT + t0 + c4];
        *(float4*)&Ws[r][c4] = *(const float4*)&Wax[(size_t)(i0 + r) * NH + h0 + c4];
        __syncthreads();
#pragma unroll
        for (int i = 0; i < 16; ++i) {
            float4 av = *(float4*)&Xs[i][r * 4];
            float4 bv = *(float4*)&Ws[i][tx * 4];
            c[0][0] += av.x * bv.x; c[0][1] += av.x * bv.y; c[0][2] += av.x * bv.z; c[0][3] += av.x * bv.w;
            c[1][0] += av.y * bv.x; c[1][1] += av.y * bv.y; c[1][2] += av.y * bv.z; c[1][3] += av.y * bv.w;
            c[2][0] += av.z * bv.x; c[2][1] += av.z * bv.y; c[2][2] += av.z * bv.z; c[2][3] += av.z * bv.w;
            c[3][0] += av.w * bv.x; c[3][1] += av.w * bv.y; c[3][2] += av.w * bv.z; c[3][3] += av.w * bv.w;
        }
        __syncthreads();
    }

    float bias[4];
#pragma unroll
    for (int j = 0; j < 4; ++j)
        bias[j] = bx[h0 + tx * 4 + j] + ba[h0 + tx * 4 + j];

#pragma unroll
    for (int ttl = 0; ttl < 4; ++ttl) {
        const int t = t0 + r * 4 + ttl;
        float4 v;
        v.x = c[ttl][0] + bias[0];
        v.y = c[ttl][1] + bias[1];
        v.z = c[ttl][2] + bias[2];
        v.w = c[ttl][3] + bias[3];
        *(float4*)&out[(size_t)t * (BB * NH) + (size_t)b * NH + h0 + tx * 4] = v;
    }
}

// ---------------------------------------------------------------------------
// K2: register-resident recurrence. 256 blocks (4 per batch), 512 threads.
// Block (b, q) owns columns h in [q*128, q*128+128) with Waa[:, cols] held
// entirely in VGPRs (128 floats/thread; 4 threads per column, each covering
// 128 k-values). Per-step cross-block exchange of a_t via double-buffered
// global array + per-batch monotonic arrive counter (AGENT-scope atomics —
// required for cross-XCD visibility, per-XCD L2s are not coherent).
// Co-residency: grid == 256 == #CUs, 1 block/CU (512 thr, VGPR<=256).
// ---------------------------------------------------------------------------
__device__ __forceinline__ float bcastf(float v, int l) {
    return __int_as_float(__builtin_amdgcn_readlane(__float_as_int(v), l));
}

__global__ __launch_bounds__(512, 2) void rnn_scan_reg(
    const float* __restrict__ Waa, float* __restrict__ out,
    float* __restrict__ Abuf, unsigned* __restrict__ flags)
{
    const int blk  = blockIdx.x;     // 0..255
    const int b    = blk >> 2;       // batch
    const int q    = blk & 3;        // column quarter
    const int tid  = threadIdx.x;
    const int c    = tid & 127;      // column within quarter
    const int h    = q * 128 + c;    // global column
    const int r    = tid >> 7;       // k-quarter (wave-uniform: 2 waves per r)
    const int lane = tid & 63;

    // --- Load this thread's 128-element weight column slice into VGPRs ---
    float w[128];
#pragma unroll
    for (int j = 0; j < 128; ++j)
        w[j] = Waa[(size_t)(r * 128 + j) * NH + h];

    __shared__ float part[4][128];

    unsigned* flag = flags + b * 16;   // 64B-padded per-batch counter
    float* outb = out + (size_t)b * NH;

    for (int t = 0; t < TT; ++t) {
        const int cur = t & 1;

        // a_t k-slice for this wave: 128 values in 2 regs (lanes 0..63).
        // AGENT-scope loads bypass L1/L2 to the coherent point.
        const float* Acur = Abuf + (size_t)cur * (BB * NH) + (size_t)b * NH + r * 128;
        float a0 = __hip_atomic_load(Acur + lane,      __ATOMIC_RELAXED, __HIP_MEMORY_SCOPE_AGENT);
        float a1 = __hip_atomic_load(Acur + 64 + lane, __ATOMIC_RELAXED, __HIP_MEMORY_SCOPE_AGENT);

        // Partial dot: wave-uniform broadcast via v_readlane (VALU pipe).
        float acc0 = 0.f, acc1 = 0.f, acc2 = 0.f, acc3 = 0.f;
#pragma unroll
        for (int j = 0; j < 64; j += 4) {
            acc0 = fmaf(w[j + 0], bcastf(a0, j + 0), acc0);
            acc1 = fmaf(w[j + 1], bcastf(a0, j + 1), acc1);
            acc2 = fmaf(w[j + 2], bcastf(a0, j + 2), acc2);
            acc3 = fmaf(w[j + 3], bcastf(a0, j + 3), acc3);
        }
#pragma unroll
        for (int j = 0; j < 64; j += 4) {
            acc0 = fmaf(w[64 + j + 0], bcastf(a1, j + 0), acc0);
            acc1 = fmaf(w[64 + j + 1], bcastf(a1, j + 1), acc1);
            acc2 = fmaf(w[64 + j + 2], bcastf(a1, j + 2), acc2);
            acc3 = fmaf(w[64 + j + 3], bcastf(a1, j + 3), acc3);
        }
        part[r][c] = (acc0 + acc1) + (acc2 + acc3);
        __syncthreads();

        if (r == 0) {
            float u  = outb[(size_t)t * (BB * NH) + h];
            float an = tanhf(u + ((part[0][c] + part[1][c]) + (part[2][c] + part[3][c])));
            outb[(size_t)t * (BB * NH) + h] = an;
            __hip_atomic_store(Abuf + (size_t)(cur ^ 1) * (BB * NH) + (size_t)b * NH + h,
                               an, __ATOMIC_RELAXED, __HIP_MEMORY_SCOPE_AGENT);
        }
        // Barrier drains vmcnt (stores issued to coherent point) for all waves
        // before thread 0 publishes the release-increment.
        __syncthreads();

        if (tid == 0) {
            __hip_atomic_fetch_add(flag, 1u, __ATOMIC_RELEASE, __HIP_MEMORY_SCOPE_AGENT);
            const unsigned target = 4u * (unsigned)(t + 1);
            while (__hip_atomic_load(flag, __ATOMIC_ACQUIRE, __HIP_MEMORY_SCOPE_AGENT) < target)
                __builtin_amdgcn_s_sleep(1);
        }
        __syncthreads();
    }
}

extern "C" void kernel_launch(void* const* d_in, const int* in_sizes, int n_in,
                              void* d_out, int out_size, void* d_ws, size_t ws_size,
                              hipStream_t stream) {
    const float* X   = (const float*)d_in[0];
    const float* Wax = (const float*)d_in[1];
    const float* Waa = (const float*)d_in[2];
    const float* bx  = (const float*)d_in[3];
    const float* ba  = (const float*)d_in[4];
    float* out = (float*)d_out;

    // Workspace: A double buffer [2][64][512] f32 (256 KB) + flags (4 KB).
    float*    Abuf  = (float*)d_ws;
    unsigned* flags = (unsigned*)((char*)d_ws + 2 * BB * NH * sizeof(float));
    const size_t init_bytes = 2 * BB * NH * sizeof(float) + 64 * 16 * sizeof(unsigned);
    hipMemsetAsync(d_ws, 0, init_bytes, stream);

    dim3 g1(NH / 64, TT / 64, BB);
    inp_proj_kernel<<<g1, 256, 0, stream>>>(X, Wax, bx, ba, out);
    rnn_scan_reg<<<256, 512, 0, stream>>>(Waa, out, Abuf, flags);
}

// Round 3
// 1494.846 us; speedup vs baseline: 3.2411x; 2.9402x over previous
//
#include <hip/hip_runtime.h>
#include <math.h>

#define BB   64
#define NIN  512
#define NH   512
#define TT   512

typedef _Float16 half2_t __attribute__((ext_vector_type(2)));

// ---------------------------------------------------------------------------
// K1: u[t][b][h] = sum_i X[b][i][t] * Wax[i][h] + bx[h] + ba[h]
// Written directly into d_out at [t][b][h]; K2 overwrites in place with a_{t+1}.
// ---------------------------------------------------------------------------
__global__ __launch_bounds__(256) void inp_proj_kernel(
    const float* __restrict__ X, const float* __restrict__ Wax,
    const float* __restrict__ bx, const float* __restrict__ ba,
    float* __restrict__ out)
{
    __shared__ float Xs[16][64];   // [i_local][t_local]
    __shared__ float Ws[16][64];   // [i_local][h_local]

    const int b   = blockIdx.z;
    const int t0  = blockIdx.y * 64;
    const int h0  = blockIdx.x * 64;
    const int tid = threadIdx.x;
    const int r   = tid >> 4;
    const int tx  = tid & 15;
    const int c4  = tx * 4;

    const float* Xb = X + (size_t)b * NIN * TT;

    float c[4][4] = {};

    for (int i0 = 0; i0 < NIN; i0 += 16) {
        *(float4*)&Xs[r][c4] = *(const float4*)&Xb[(size_t)(i0 + r) * TT + t0 + c4];
        *(float4*)&Ws[r][c4] = *(const float4*)&Wax[(size_t)(i0 + r) * NH + h0 + c4];
        __syncthreads();
#pragma unroll
        for (int i = 0; i < 16; ++i) {
            float4 av = *(float4*)&Xs[i][r * 4];
            float4 bv = *(float4*)&Ws[i][tx * 4];
            c[0][0] += av.x * bv.x; c[0][1] += av.x * bv.y; c[0][2] += av.x * bv.z; c[0][3] += av.x * bv.w;
            c[1][0] += av.y * bv.x; c[1][1] += av.y * bv.y; c[1][2] += av.y * bv.z; c[1][3] += av.y * bv.w;
            c[2][0] += av.z * bv.x; c[2][1] += av.z * bv.y; c[2][2] += av.z * bv.z; c[2][3] += av.z * bv.w;
            c[3][0] += av.w * bv.x; c[3][1] += av.w * bv.y; c[3][2] += av.w * bv.z; c[3][3] += av.w * bv.w;
        }
        __syncthreads();
    }

    float bias[4];
#pragma unroll
    for (int j = 0; j < 4; ++j)
        bias[j] = bx[h0 + tx * 4 + j] + ba[h0 + tx * 4 + j];

#pragma unroll
    for (int ttl = 0; ttl < 4; ++ttl) {
        const int t = t0 + r * 4 + ttl;
        float4 v;
        v.x = c[ttl][0] + bias[0];
        v.y = c[ttl][1] + bias[1];
        v.z = c[ttl][2] + bias[2];
        v.w = c[ttl][3] + bias[3];
        *(float4*)&out[(size_t)t * (BB * NH) + (size_t)b * NH + h0 + tx * 4] = v;
    }
}

// ---------------------------------------------------------------------------
// K2: one block per batch (64 blocks x 512 threads). Whole Waa on one CU as
// fp16: thread h owns column h. Pairs 0..207 (k=0..415) in VGPRs (208 dwords),
// pairs 208..255 (k=416..511) in LDS (96 KB). Per step:
//   - each lane's a_t held replicated per-wave as 4 packed-half2 dwords
//   - 256 x v_dot2_f32_f16 with v_readlane broadcast (fp32 accumulate)
//   - tanh, global store, LDS half-exchange, ONE raw s_barrier (no vmcnt
//     drain: keeps the out-store and the u[t+1] prefetch in flight).
// No cross-block communication at all.
// ---------------------------------------------------------------------------
#define NREG 208                // half2 pairs per column held in VGPRs
#define NLDS 24                 // uint2 (2 pairs) per column held in LDS

__device__ __forceinline__ half2_t bpair(unsigned a, int l) {
    unsigned d = (unsigned)__builtin_amdgcn_readlane((int)a, l);
    return __builtin_bit_cast(half2_t, d);
}

__device__ __forceinline__ float tanh_fast(float x) {
    float ax = __builtin_fabsf(x);
    float e  = __builtin_amdgcn_exp2f(-2.885390082f * ax);   // exp(-2|x|)
    float r  = (1.0f - e) * __builtin_amdgcn_rcpf(1.0f + e);
    return __builtin_copysignf(r, x);
}

__global__ __launch_bounds__(512, 2) void rnn_scan_lds(
    const float* __restrict__ Waa, float* __restrict__ out)
{
    __shared__ uint2    wl[NLDS][NH];     // 96 KB: pairs 208+2q, 208+2q+1 per col
    __shared__ unsigned exch[2][256];     // 2 KB: a_t as packed half2, dbl-buffered

    const int b    = blockIdx.x;
    const int h    = threadIdx.x;         // column owned by this thread
    const int lane = threadIdx.x & 63;

    // ---- preamble: load fp32 Waa column h, convert to packed fp16 pairs ----
    unsigned w_pk[NREG];
#pragma unroll
    for (int j = 0; j < NREG; ++j) {
        float w0 = Waa[(size_t)(2 * j)     * NH + h];
        float w1 = Waa[(size_t)(2 * j + 1) * NH + h];
        unsigned lo = (unsigned)__builtin_bit_cast(unsigned short, (_Float16)w0);
        unsigned hi = (unsigned)__builtin_bit_cast(unsigned short, (_Float16)w1);
        w_pk[j] = lo | (hi << 16);
    }
#pragma unroll
    for (int q = 0; q < NLDS; ++q) {
        int kp = NREG + 2 * q;            // pair index
        uint2 v;
        {
            float w0 = Waa[(size_t)(2 * kp)     * NH + h];
            float w1 = Waa[(size_t)(2 * kp + 1) * NH + h];
            v.x = (unsigned)__builtin_bit_cast(unsigned short, (_Float16)w0) |
                  ((unsigned)__builtin_bit_cast(unsigned short, (_Float16)w1) << 16);
        }
        {
            float w0 = Waa[(size_t)(2 * kp + 2) * NH + h];
            float w1 = Waa[(size_t)(2 * kp + 3) * NH + h];
            v.y = (unsigned)__builtin_bit_cast(unsigned short, (_Float16)w0) |
                  ((unsigned)__builtin_bit_cast(unsigned short, (_Float16)w1) << 16);
        }
        wl[q][h] = v;
    }
    __syncthreads();

    // a_0 = 0: replicated packed state, 4 dwords per lane (pair p = r*64+lane)
    unsigned a0 = 0, a1 = 0, a2 = 0, a3 = 0;

    float* ob = out + (size_t)b * NH + h;
    float u_cur = ob[0];

    for (int t = 0; t < TT; ++t) {
        // prefetch next step's input projection (hidden under compute)
        const int tn = (t + 1 < TT) ? (t + 1) : (TT - 1);
        float u_next = ob[(size_t)tn * (BB * NH)];

        float acc0 = 0.f, acc1 = 0.f, acc2 = 0.f, acc3 = 0.f;
#pragma unroll
        for (int j = 0; j < 64; j += 4) {
            acc0 = __builtin_amdgcn_fdot2(__builtin_bit_cast(half2_t, w_pk[j + 0]), bpair(a0, j + 0), acc0, false);
            acc1 = __builtin_amdgcn_fdot2(__builtin_bit_cast(half2_t, w_pk[j + 1]), bpair(a0, j + 1), acc1, false);
            acc2 = __builtin_amdgcn_fdot2(__builtin_bit_cast(half2_t, w_pk[j + 2]), bpair(a0, j + 2), acc2, false);
            acc3 = __builtin_amdgcn_fdot2(__builtin_bit_cast(half2_t, w_pk[j + 3]), bpair(a0, j + 3), acc3, false);
        }
#pragma unroll
        for (int j = 0; j < 64; j += 4) {
            acc0 = __builtin_amdgcn_fdot2(__builtin_bit_cast(half2_t, w_pk[64 + j + 0]), bpair(a1, j + 0), acc0, false);
            acc1 = __builtin_amdgcn_fdot2(__builtin_bit_cast(half2_t, w_pk[64 + j + 1]), bpair(a1, j + 1), acc1, false);
            acc2 = __builtin_amdgcn_fdot2(__builtin_bit_cast(half2_t, w_pk[64 + j + 2]), bpair(a1, j + 2), acc2, false);
            acc3 = __builtin_amdgcn_fdot2(__builtin_bit_cast(half2_t, w_pk[64 + j + 3]), bpair(a1, j + 3), acc3, false);
        }
#pragma unroll
        for (int j = 0; j < 64; j += 4) {
            acc0 = __builtin_amdgcn_fdot2(__builtin_bit_cast(half2_t, w_pk[128 + j + 0]), bpair(a2, j + 0), acc0, false);
            acc1 = __builtin_amdgcn_fdot2(__builtin_bit_cast(half2_t, w_pk[128 + j + 1]), bpair(a2, j + 1), acc1, false);
            acc2 = __builtin_amdgcn_fdot2(__builtin_bit_cast(half2_t, w_pk[128 + j + 2]), bpair(a2, j + 2), acc2, false);
            acc3 = __builtin_amdgcn_fdot2(__builtin_bit_cast(half2_t, w_pk[128 + j + 3]), bpair(a2, j + 3), acc3, false);
        }
#pragma unroll
        for (int j = 0; j < 16; j += 4) {   // pairs 192..207 from a3 lanes 0..15
            acc0 = __builtin_amdgcn_fdot2(__builtin_bit_cast(half2_t, w_pk[192 + j + 0]), bpair(a3, j + 0), acc0, false);
            acc1 = __builtin_amdgcn_fdot2(__builtin_bit_cast(half2_t, w_pk[192 + j + 1]), bpair(a3, j + 1), acc1, false);
            acc2 = __builtin_amdgcn_fdot2(__builtin_bit_cast(half2_t, w_pk[192 + j + 2]), bpair(a3, j + 2), acc2, false);
            acc3 = __builtin_amdgcn_fdot2(__builtin_bit_cast(half2_t, w_pk[192 + j + 3]), bpair(a3, j + 3), acc3, false);
        }
        // LDS-resident pairs 208..255 (a3 lanes 16..63)
#pragma unroll
        for (int q = 0; q < NLDS; q += 2) {
            uint2 v0 = wl[q][h];
            uint2 v1 = wl[q + 1][h];
            acc0 = __builtin_amdgcn_fdot2(__builtin_bit_cast(half2_t, v0.x), bpair(a3, 16 + 2 * q + 0), acc0, false);
            acc1 = __builtin_amdgcn_fdot2(__builtin_bit_cast(half2_t, v0.y), bpair(a3, 16 + 2 * q + 1), acc1, false);
            acc2 = __builtin_amdgcn_fdot2(__builtin_bit_cast(half2_t, v1.x), bpair(a3, 16 + 2 * q + 2), acc2, false);
            acc3 = __builtin_amdgcn_fdot2(__builtin_bit_cast(half2_t, v1.y), bpair(a3, 16 + 2 * q + 3), acc3, false);
        }

        float x  = u_cur + ((acc0 + acc1) + (acc2 + acc3));
        float an = tanh_fast(x);
        ob[(size_t)t * (BB * NH)] = an;     // fire-and-forget global store
        u_cur = u_next;

        // ---- a-exchange via LDS (double-buffered, one raw barrier) ----
        const int buf = t & 1;
        ((unsigned short*)exch[buf])[h] =
            __builtin_bit_cast(unsigned short, (_Float16)an);
        __builtin_amdgcn_s_waitcnt(0xC07F);   // lgkmcnt(0): own ds_write visible
        __builtin_amdgcn_s_barrier();         // raw: no vmcnt drain
        a0 = exch[buf][lane];
        a1 = exch[buf][64 + lane];
        a2 = exch[buf][128 + lane];
        a3 = exch[buf][192 + lane];
        // reads are consumed next iteration before buf is rewritten (t+2),
        // and the t+1 barrier orders them against the overwrite.
    }
}

extern "C" void kernel_launch(void* const* d_in, const int* in_sizes, int n_in,
                              void* d_out, int out_size, void* d_ws, size_t ws_size,
                              hipStream_t stream) {
    const float* X   = (const float*)d_in[0];
    const float* Wax = (const float*)d_in[1];
    const float* Waa = (const float*)d_in[2];
    const float* bx  = (const float*)d_in[3];
    const float* ba  = (const float*)d_in[4];
    float* out = (float*)d_out;

    dim3 g1(NH / 64, TT / 64, BB);
    inp_proj_kernel<<<g1, 256, 0, stream>>>(X, Wax, bx, ba, out);
    rnn_scan_lds<<<BB, NH, 0, stream>>>(Waa, out);
}